// Round 1
// baseline (5132.763 us; speedup 1.0000x reference)
//
#include <hip/hip_runtime.h>
#include <cstdint>
#include <cstddef>

typedef unsigned short u16;
typedef __bf16 bf16_t;
typedef bf16_t bf16x8 __attribute__((ext_vector_type(8)));
typedef float f32x4 __attribute__((ext_vector_type(4)));

static constexpr int HID    = 512;
static constexpr int BATCH  = 1024;
static constexpr int NSTEPS = 95;   // T + future - 1 = 64 + 31
static constexpr int T_OBS  = 64;
static constexpr int OUTW   = 190;  // 2 * NSTEPS

// ---------- helpers ----------
__device__ __forceinline__ u16 f2bf(float x) {
  union { float f; uint32_t u; } c; c.f = x;
  uint32_t r = c.u + 0x7fffu + ((c.u >> 16) & 1u);   // round-to-nearest-even
  return (u16)(r >> 16);
}
__device__ __forceinline__ float bf2f(u16 h) {
  union { uint32_t u; float f; } c; c.u = ((uint32_t)h) << 16;
  return c.f;
}
__device__ __forceinline__ float sigm(float x) { return 1.f / (1.f + __expf(-x)); }
__device__ __forceinline__ float tanh_fast(float x) {
  float ax = fabsf(x);
  float t  = __expf(-2.f * ax);          // t in (0,1], no overflow
  float r  = (1.f - t) / (1.f + t);
  return x < 0.f ? -r : r;
}

// ---------- weight prep ----------
// Gate-interleaved column order: col n = 4*h + g  <->  original row r = g*512 + h
// Bt1: [2048][1024] bf16 : cols 0..511 = hi(Whh1[r][k]), 512..1023 = lo
__global__ void prep_bt1(const float* __restrict__ Whh1, u16* __restrict__ Bt1) {
  int idx = blockIdx.x * 256 + threadIdx.x;       // 2048*1024
  int n = idx >> 10, kk = idx & 1023;
  int r = (n & 3) * HID + (n >> 2);
  int k = kk & 511;
  float v = Whh1[r * HID + k];
  u16 hi = f2bf(v);
  Bt1[idx] = (kk < 512) ? hi : f2bf(v - bf2f(hi));
}
// Bt2: [2048][2048] bf16 : k<512 from Wih2, 512..1023 from Whh2; cols 0..1023 hi, 1024..2047 lo
__global__ void prep_bt2(const float* __restrict__ Wih2, const float* __restrict__ Whh2,
                         u16* __restrict__ Bt2) {
  int idx = blockIdx.x * 256 + threadIdx.x;       // 2048*2048
  int n = idx >> 11, kk = idx & 2047;
  int r = (n & 3) * HID + (n >> 2);
  int k = kk & 1023;
  float v = (k < 512) ? Wih2[r * HID + k] : Whh2[r * HID + (k - 512)];
  u16 hi = f2bf(v);
  Bt2[idx] = (kk < 1024) ? hi : f2bf(v - bf2f(hi));
}
__global__ void prep_small(const float* __restrict__ b1, const float* __restrict__ b2,
                           const float* __restrict__ Wih1,
                           float* __restrict__ b1p, float* __restrict__ b2p,
                           float* __restrict__ w1p) {
  int n = blockIdx.x * 256 + threadIdx.x;
  if (n >= 2048) return;
  int r = (n & 3) * HID + (n >> 2);
  b1p[n] = b1[r];
  b2p[n] = b2[r];
  w1p[2 * n + 0] = Wih1[2 * r + 0];
  w1p[2 * n + 1] = Wih1[2 * r + 1];
}

// ---------- fused gate-GEMM + LSTM cell ----------
// C[1024, 2048] = A' @ B' (3-pass bf16 hi/lo emulation of fp32), then epilogue:
// gates += bias (+ x @ Wih1^T for layer 1), activations, c/h update,
// h written as bf16 hi + lo for the next step's GEMM.
struct GemmArgs {
  const u16* Ah0; const u16* Ah1;   // hi activation chunks ([1024][512] each)
  const u16* Al0; const u16* Al1;   // lo activation chunks
  const u16* Bt;  int bstride;      // bf16 weight panel, row stride in elements
  const float* bias;                // reordered bias [2048]
  const float* xptr; int xstride;   // layer-1 input (2 floats/row), else null
  const float* wih;                 // reordered Wih1 [2048][2], else null
  float* Cst;                       // cell state [1024][512], RMW
  u16* Hh; u16* Hl;                 // output h hi/lo [1024][512]
};

template <int NCH, bool HASX>      // NCH: 3 (layer1) or 6 (layer2) 512-wide K chunks
__global__ __launch_bounds__(256, 2) void lstm_gemm(GemmArgs a) {
  __shared__ __align__(16) char smem[18432];
  u16* As = (u16*)smem;              // [64][72] bf16 (+8 pad)
  u16* Bs = (u16*)(smem + 9216);     // [64][72]

  const int tid = threadIdx.x;
  const int bid = blockIdx.x;
  const int nt = bid & 31;           // 32 N-tiles (64 gate cols = 16 h)
  const int mt = bid >> 5;           // 16 M-tiles (64 rows)
  const int wid = tid >> 6, lane = tid & 63;
  const int wm = wid >> 1, wn = wid & 1;

  const int r0 = tid >> 3;           // 0..31
  const int sl = tid & 7;            // 16B slot in a 128B row

  f32x4 acc[2][2] = {};

  auto loadA = [&](int ks, uint4& ra0, uint4& ra1, uint4& rb0, uint4& rb1) {
    int c = ks >> 3, k0 = (ks & 7) * 64;
    const u16* Ab; int boff;
    if (NCH == 3) {  // chunks {Ah0, Ah0, Al0} x B {hi, lo, hi}
      Ab = (c < 2) ? a.Ah0 : a.Al0;
      boff = (c == 1) ? 512 : 0;
    } else {         // chunks {Ah0,Ah1,Ah0,Ah1,Al0,Al1} x B {hi,hi,lo,lo,hi,hi}
      Ab = (c < 4) ? ((c & 1) ? a.Ah1 : a.Ah0) : ((c & 1) ? a.Al1 : a.Al0);
      boff = (c < 4) ? c * 512 : (c - 4) * 512;
    }
    const u16* Ap = Ab + (size_t)(mt * 64) * HID + k0 + sl * 8;
    const u16* Bp = a.Bt + (size_t)(nt * 64) * a.bstride + boff + k0 + sl * 8;
    ra0 = *(const uint4*)(Ap + (size_t)r0 * HID);
    ra1 = *(const uint4*)(Ap + (size_t)(r0 + 32) * HID);
    rb0 = *(const uint4*)(Bp + (size_t)r0 * a.bstride);
    rb1 = *(const uint4*)(Bp + (size_t)(r0 + 32) * a.bstride);
  };

  constexpr int TOT = NCH * 8;
  uint4 ra0, ra1, rb0, rb1;
  loadA(0, ra0, ra1, rb0, rb1);

  for (int ks = 0; ks < TOT; ++ks) {
    __syncthreads();                               // prev compute done
    *(uint4*)(As + r0 * 72 + sl * 8)        = ra0;
    *(uint4*)(As + (r0 + 32) * 72 + sl * 8) = ra1;
    *(uint4*)(Bs + r0 * 72 + sl * 8)        = rb0;
    *(uint4*)(Bs + (r0 + 32) * 72 + sl * 8) = rb1;
    __syncthreads();
    int ksn = (ks + 1 < TOT) ? ks + 1 : ks;        // prefetch next (redundant last)
    uint4 na0, na1, nb0, nb1;
    loadA(ksn, na0, na1, nb0, nb1);
#pragma unroll
    for (int kk = 0; kk < 2; ++kk) {
      const int ko = kk * 32 + (lane >> 4) * 8;
      bf16x8 a0 = *(const bf16x8*)(As + (wm * 32 +  0 + (lane & 15)) * 72 + ko);
      bf16x8 a1 = *(const bf16x8*)(As + (wm * 32 + 16 + (lane & 15)) * 72 + ko);
      bf16x8 b0 = *(const bf16x8*)(Bs + (wn * 32 +  0 + (lane & 15)) * 72 + ko);
      bf16x8 b1 = *(const bf16x8*)(Bs + (wn * 32 + 16 + (lane & 15)) * 72 + ko);
      acc[0][0] = __builtin_amdgcn_mfma_f32_16x16x32_bf16(a0, b0, acc[0][0], 0, 0, 0);
      acc[0][1] = __builtin_amdgcn_mfma_f32_16x16x32_bf16(a0, b1, acc[0][1], 0, 0, 0);
      acc[1][0] = __builtin_amdgcn_mfma_f32_16x16x32_bf16(a1, b0, acc[1][0], 0, 0, 0);
      acc[1][1] = __builtin_amdgcn_mfma_f32_16x16x32_bf16(a1, b1, acc[1][1], 0, 0, 0);
    }
    ra0 = na0; ra1 = na1; rb0 = nb0; rb1 = nb1;
  }

  // ---- epilogue: C to LDS, then fused LSTM cell ----
  __syncthreads();
  float* Cl = (float*)smem;                        // [64][65]
#pragma unroll
  for (int mi = 0; mi < 2; ++mi)
#pragma unroll
    for (int ni = 0; ni < 2; ++ni)
#pragma unroll
      for (int r = 0; r < 4; ++r) {
        int row = wm * 32 + mi * 16 + (lane >> 4) * 4 + r;   // M index
        int col = wn * 32 + ni * 16 + (lane & 15);           // N index
        Cl[row * 65 + col] = acc[mi][ni][r];
      }
  __syncthreads();

  const int mg0 = mt * 64;
  const int hg0 = nt * 16;
#pragma unroll
  for (int q = 0; q < 4; ++q) {
    int idx = q * 256 + tid;          // 0..1023 : 64 rows x 16 h
    int m = idx >> 4, hl = idx & 15;
    int mg = mg0 + m, hg = hg0 + hl;
    int nb = hg * 4;
    float g0 = Cl[m * 65 + hl * 4 + 0] + a.bias[nb + 0];
    float g1 = Cl[m * 65 + hl * 4 + 1] + a.bias[nb + 1];
    float g2 = Cl[m * 65 + hl * 4 + 2] + a.bias[nb + 2];
    float g3 = Cl[m * 65 + hl * 4 + 3] + a.bias[nb + 3];
    if (HASX) {
      float x0 = a.xptr[(size_t)mg * a.xstride + 0];
      float x1 = a.xptr[(size_t)mg * a.xstride + 1];
      g0 += x0 * a.wih[(nb + 0) * 2] + x1 * a.wih[(nb + 0) * 2 + 1];
      g1 += x0 * a.wih[(nb + 1) * 2] + x1 * a.wih[(nb + 1) * 2 + 1];
      g2 += x0 * a.wih[(nb + 2) * 2] + x1 * a.wih[(nb + 2) * 2 + 1];
      g3 += x0 * a.wih[(nb + 3) * 2] + x1 * a.wih[(nb + 3) * 2 + 1];
    }
    float ig = sigm(g0), fg = sigm(g1), gg = tanh_fast(g2), og = sigm(g3);
    float cp = a.Cst[(size_t)mg * HID + hg];
    float cn = fg * cp + ig * gg;
    a.Cst[(size_t)mg * HID + hg] = cn;
    float hn = og * tanh_fast(cn);
    u16 hi = f2bf(hn);
    a.Hh[(size_t)mg * HID + hg] = hi;
    a.Hl[(size_t)mg * HID + hg] = f2bf(hn - bf2f(hi));
  }
}

// ---------- output projection: out[b,2] = (Hh+Hl) @ Wl^T + bl ----------
__global__ __launch_bounds__(256) void out_proj(const u16* __restrict__ Hh,
                                                const u16* __restrict__ Hl,
                                                const float* __restrict__ Wl,
                                                const float* __restrict__ bl,
                                                float* __restrict__ obase) {
  int b = blockIdx.x * 4 + (threadIdx.x >> 6);
  int lane = threadIdx.x & 63;
  float s0 = 0.f, s1 = 0.f;
#pragma unroll
  for (int j0 = 0; j0 < HID; j0 += 64) {
    int j = j0 + lane;
    float h = bf2f(Hh[(size_t)b * HID + j]) + bf2f(Hl[(size_t)b * HID + j]);
    s0 += h * Wl[j];
    s1 += h * Wl[HID + j];
  }
#pragma unroll
  for (int off = 32; off > 0; off >>= 1) {
    s0 += __shfl_down(s0, off);
    s1 += __shfl_down(s1, off);
  }
  if (lane == 0) {
    obase[(size_t)b * OUTW + 0] = s0 + bl[0];
    obase[(size_t)b * OUTW + 1] = s1 + bl[1];
  }
}

// ---------- host ----------
extern "C" void kernel_launch(void* const* d_in, const int* in_sizes, int n_in,
                              void* d_out, int out_size, void* d_ws, size_t ws_size,
                              hipStream_t stream) {
  const float* x    = (const float*)d_in[0];
  const float* Wih1 = (const float*)d_in[1];
  const float* Whh1 = (const float*)d_in[2];
  const float* b1   = (const float*)d_in[3];
  const float* Wih2 = (const float*)d_in[4];
  const float* Whh2 = (const float*)d_in[5];
  const float* b2   = (const float*)d_in[6];
  const float* Wl   = (const float*)d_in[7];
  const float* bl   = (const float*)d_in[8];
  float* out = (float*)d_out;
  (void)in_sizes; (void)n_in; (void)out_size; (void)ws_size;

  char* p = (char*)d_ws;
  auto alloc = [&](size_t bytes) -> char* {
    char* r = p; p += (bytes + 255) & ~(size_t)255; return r;
  };
  u16* Bt1 = (u16*)alloc((size_t)2048 * 1024 * 2);   // 4 MB
  u16* Bt2 = (u16*)alloc((size_t)2048 * 2048 * 2);   // 8 MB
  char* state0 = p;
  u16* Hb[8];                                        // H1h[2],H1l[2],H2h[2],H2l[2]
  for (int i = 0; i < 8; ++i) Hb[i] = (u16*)alloc((size_t)BATCH * HID * 2);
  float* C1 = (float*)alloc((size_t)BATCH * HID * 4);
  float* C2 = (float*)alloc((size_t)BATCH * HID * 4);
  size_t state_bytes = (size_t)(p - state0);
  float* b1p = (float*)alloc(2048 * 4);
  float* b2p = (float*)alloc(2048 * 4);
  float* w1p = (float*)alloc(2048 * 2 * 4);

  hipMemsetAsync(state0, 0, state_bytes, stream);    // h,c = 0
  prep_bt1<<<8192, 256, 0, stream>>>(Whh1, Bt1);
  prep_bt2<<<16384, 256, 0, stream>>>(Wih2, Whh2, Bt2);
  prep_small<<<8, 256, 0, stream>>>(b1, b2, Wih1, b1p, b2p, w1p);

  for (int t = 0; t < NSTEPS; ++t) {
    int par = t & 1, prev = par ^ 1;
    u16 *H1h_p = Hb[0 + prev], *H1l_p = Hb[2 + prev];
    u16 *H1h_c = Hb[0 + par],  *H1l_c = Hb[2 + par];
    u16 *H2h_p = Hb[4 + prev], *H2l_p = Hb[6 + prev];
    u16 *H2h_c = Hb[4 + par],  *H2l_c = Hb[6 + par];

    GemmArgs a1{};
    a1.Ah0 = H1h_p; a1.Ah1 = nullptr; a1.Al0 = H1l_p; a1.Al1 = nullptr;
    a1.Bt = Bt1; a1.bstride = 1024; a1.bias = b1p;
    a1.xptr = (t < T_OBS) ? (x + 2 * t) : (out + 2 * (t - 1));
    a1.xstride = (t < T_OBS) ? (2 * T_OBS) : OUTW;
    a1.wih = w1p; a1.Cst = C1; a1.Hh = H1h_c; a1.Hl = H1l_c;
    lstm_gemm<3, true><<<512, 256, 0, stream>>>(a1);

    GemmArgs a2{};
    a2.Ah0 = H1h_c; a2.Ah1 = H2h_p; a2.Al0 = H1l_c; a2.Al1 = H2l_p;
    a2.Bt = Bt2; a2.bstride = 2048; a2.bias = b2p;
    a2.xptr = nullptr; a2.xstride = 0; a2.wih = nullptr;
    a2.Cst = C2; a2.Hh = H2h_c; a2.Hl = H2l_c;
    lstm_gemm<6, false><<<512, 256, 0, stream>>>(a2);

    out_proj<<<256, 256, 0, stream>>>(H2h_c, H2l_c, Wl, bl, out + 2 * t);
  }
}